// Round 5
// baseline (1820.195 us; speedup 1.0000x reference)
//
#include <hip/hip_runtime.h>
#include <hip/hip_bf16.h>
#include <math.h>

#define BN_INVF 0.9999950000374998f
#define LN_EPSF 1e-5f

typedef __attribute__((ext_vector_type(8))) short bf16x8;
typedef __attribute__((ext_vector_type(4))) float f32x4;

__device__ inline unsigned short f2bf(float v) {
    __hip_bfloat16 h = __float2bfloat16(v);
    return *(const unsigned short*)&h;
}

// ---------------- small helpers ----------------

__device__ inline float block_sum256(float v, float* sbuf) {
    for (int off = 32; off; off >>= 1) v += __shfl_down(v, off);
    int lane = threadIdx.x & 63, w = threadIdx.x >> 6;
    if (lane == 0) sbuf[w] = v;
    __syncthreads();
    float r;
    if (threadIdx.x == 0) { r = sbuf[0] + sbuf[1] + sbuf[2] + sbuf[3]; sbuf[0] = r; }
    __syncthreads();
    r = sbuf[0];
    __syncthreads();
    return r;
}

__device__ inline unsigned fkey(float v) {
    unsigned u = __float_as_uint(v);
    return (u & 0x80000000u) ? ~u : (u | 0x80000000u);
}

// ---------------- kernels ----------------

// xx[g] = sum_c x[g-row][c]^2, point-major rows; 4 lanes per row
__global__ void xx_kernel(const float* __restrict__ x, float* __restrict__ xx,
                          int C, int lda, long long bstr) {
    int g = blockIdx.x * 64 + (threadIdx.x >> 2);
    int q = threadIdx.x & 3;
    if (g >= 2 * 2048) return;
    int b = g >> 11, n = g & 2047;
    const float* p = x + (long long)b * bstr + (long long)n * lda;
    float s = 0.f;
    for (int c = q; c < C; c += 4) { float v = p[c]; s = fmaf(v, v, s); }
    s += __shfl_down(s, 1);
    s += __shfl_down(s, 2);
    if (q == 0) xx[g] = s;
}

// fp32 NT GEMM: C[m][n] = sum_k A[m][k]*B[n][k].  modes: 0 plain | 4: 2*acc-xx[m]-xx[n]
__launch_bounds__(256)
__global__ void gemm_nt_kernel(const float* __restrict__ A, const float* __restrict__ Bm,
                               float* __restrict__ Cm, const float* __restrict__ vrow,
                               int M, int N, int Kd, int lda, int ldb, int ldc,
                               long long sA, long long sB, long long sC, int mode) {
    int tid = threadIdx.x;
    int tx = tid & 15, ty = tid >> 4;
    int m0 = blockIdx.y * 64, n0 = blockIdx.x * 64;
    A  += (long long)blockIdx.z * sA;
    Bm += (long long)blockIdx.z * sB;
    Cm += (long long)blockIdx.z * sC;

    __shared__ float As[16][68];
    __shared__ float Bs[16][68];
    float acc[4][4] = {};
    const bool vec = ((Kd & 15) == 0);

    for (int k0 = 0; k0 < Kd; k0 += 16) {
        if (vec) {
            int row = tid >> 2, q = tid & 3;
            float4 f = *(const float4*)&A[(long long)(m0 + row) * lda + k0 + q * 4];
            As[q * 4 + 0][row] = f.x; As[q * 4 + 1][row] = f.y;
            As[q * 4 + 2][row] = f.z; As[q * 4 + 3][row] = f.w;
            float4 g = *(const float4*)&Bm[(long long)(n0 + row) * ldb + k0 + q * 4];
            Bs[q * 4 + 0][row] = g.x; Bs[q * 4 + 1][row] = g.y;
            Bs[q * 4 + 2][row] = g.z; Bs[q * 4 + 3][row] = g.w;
        } else {
#pragma unroll
            for (int e = 0; e < 4; e++) {
                int i = tid + e * 256;
                int kk = i & 15, mm = i >> 4;
                int gk = k0 + kk;
                As[kk][mm] = (gk < Kd) ? A[(long long)(m0 + mm) * lda + gk] : 0.f;
            }
#pragma unroll
            for (int e = 0; e < 4; e++) {
                int i = tid + e * 256;
                int kk = i & 15, nn = i >> 4;
                int gk = k0 + kk;
                Bs[kk][nn] = (gk < Kd) ? Bm[(long long)(n0 + nn) * ldb + gk] : 0.f;
            }
        }
        __syncthreads();
#pragma unroll
        for (int kk = 0; kk < 16; kk++) {
            float4 av = *(const float4*)&As[kk][ty * 4];
            float4 bv = *(const float4*)&Bs[kk][tx * 4];
            float a4[4] = {av.x, av.y, av.z, av.w};
            float b4[4] = {bv.x, bv.y, bv.z, bv.w};
#pragma unroll
            for (int i = 0; i < 4; i++)
#pragma unroll
                for (int j = 0; j < 4; j++)
                    acc[i][j] = fmaf(a4[i], b4[j], acc[i][j]);
        }
        __syncthreads();
    }

    const float* xxb = (mode == 4) ? vrow + (long long)blockIdx.z * M : nullptr;
#pragma unroll
    for (int i = 0; i < 4; i++) {
        int m = m0 + ty * 4 + i;
#pragma unroll
        for (int j = 0; j < 4; j++) {
            int n = n0 + tx * 4 + j;
            float v = acc[i][j];
            if (mode == 4) v = 2.f * v - xxb[m] - xxb[n];
            Cm[(long long)m * ldc + n] = v;
        }
    }
}

// bf16 MFMA NT GEMM: 128x128 tile, bk=32. mode 0: plain; 1: lrelu(bn[col]).
__launch_bounds__(256)
__global__ void mfma_nt_kernel(const unsigned short* __restrict__ A,
                               const unsigned short* __restrict__ Bv,
                               float* __restrict__ C, const float* __restrict__ bn,
                               int Nr, int K, int lda, int ldb, int ldc,
                               long long sA, long long sC, int mode) {
    int tid = threadIdx.x;
    int wave = tid >> 6, lane = tid & 63;
    int wm = (wave >> 1) * 64, wn = (wave & 1) * 64;
    int m0 = blockIdx.y * 128, n0 = blockIdx.x * 128;
    A += (long long)blockIdx.z * sA;
    C += (long long)blockIdx.z * sC;

    __shared__ __align__(16) unsigned short As[128 * 40];
    __shared__ __align__(16) unsigned short Bs[128 * 40];
    f32x4 acc[4][4];
#pragma unroll
    for (int i = 0; i < 4; i++)
#pragma unroll
        for (int j = 0; j < 4; j++) acc[i][j] = (f32x4){0.f, 0.f, 0.f, 0.f};

    int lr = lane & 15, lk = (lane >> 4) * 8;

    for (int k0 = 0; k0 < K; k0 += 32) {
#pragma unroll
        for (int e = 0; e < 2; e++) {
            int idx = tid + e * 256;
            int row = idx >> 2, q = idx & 3;
            float4 f = *(const float4*)&A[(long long)(m0 + row) * lda + k0 + q * 8];
            *(float4*)&As[row * 40 + q * 8] = f;
        }
#pragma unroll
        for (int e = 0; e < 2; e++) {
            int idx = tid + e * 256;
            int row = idx >> 2, q = idx & 3;
            float4 f = *(const float4*)&Bv[(long long)(n0 + row) * ldb + k0 + q * 8];
            *(float4*)&Bs[row * 40 + q * 8] = f;
        }
        __syncthreads();
        bf16x8 af[4], bf[4];
#pragma unroll
        for (int t = 0; t < 4; t++) af[t] = *(const bf16x8*)&As[(wm + t * 16 + lr) * 40 + lk];
#pragma unroll
        for (int t = 0; t < 4; t++) bf[t] = *(const bf16x8*)&Bs[(wn + t * 16 + lr) * 40 + lk];
#pragma unroll
        for (int i = 0; i < 4; i++)
#pragma unroll
            for (int j = 0; j < 4; j++)
                acc[i][j] = __builtin_amdgcn_mfma_f32_16x16x32_bf16(af[i], bf[j], acc[i][j], 0, 0, 0);
        __syncthreads();
    }

    int cr = (lane >> 4) << 2;
#pragma unroll
    for (int i = 0; i < 4; i++) {
        int rbase = m0 + wm + i * 16 + cr;
#pragma unroll
        for (int j = 0; j < 4; j++) {
            int col = n0 + wn + j * 16 + (lane & 15);
            float bsc = 0.f, bsh = 0.f;
            if (mode == 1) { bsc = bn[col]; bsh = bn[Nr + col]; }
#pragma unroll
            for (int r = 0; r < 4; r++) {
                float v = acc[i][j][r];
                if (mode == 1) {
                    v = bsc * (v * BN_INVF) + bsh;
                    v = v > 0.f ? v : 0.2f * v;
                }
                C[(long long)(rbase + r) * ldc + col] = v;
            }
        }
    }
}

// Skinny GEMM (transformer): A (130 x K) @ B (K x N), split-K, atomicAdd into C.
#define SK_M 130
#define SK_SLOTS 144
#define SK_PAD 145
__launch_bounds__(256)
__global__ void skinny_atomic_kernel(const float* __restrict__ A, const float* __restrict__ B,
                                     float* __restrict__ C, int N, int K, int lda, int S) {
    int tid = threadIdx.x, tx = tid & 15, ty = tid >> 4;
    int n0 = blockIdx.x * 64;
    int s = blockIdx.y;
    int kchunk = K / S;
    int k0 = s * kchunk;

    __shared__ float As[16][SK_PAD];
    __shared__ float Bs[16][64];
    float acc[9][4] = {};

    for (int kc = k0; kc < k0 + kchunk; kc += 16) {
#pragma unroll
        for (int e = 0; e < 3; e++) {
            int idx = tid + e * 256;
            if (idx < SK_SLOTS * 4) {
                int m = idx >> 2, kq = idx & 3;
                float4 f = make_float4(0.f, 0.f, 0.f, 0.f);
                if (m < SK_M) f = *(const float4*)&A[(long long)m * lda + kc + kq * 4];
                As[kq * 4 + 0][m] = f.x;
                As[kq * 4 + 1][m] = f.y;
                As[kq * 4 + 2][m] = f.z;
                As[kq * 4 + 3][m] = f.w;
            }
        }
        {
            int kk = tid >> 4, nq = tid & 15;
            float4 g = *(const float4*)&B[(long long)(kc + kk) * N + n0 + nq * 4];
            *(float4*)&Bs[kk][nq * 4] = g;
        }
        __syncthreads();
#pragma unroll
        for (int kk = 0; kk < 16; kk++) {
            float4 bv = *(const float4*)&Bs[kk][tx * 4];
            float b4[4] = {bv.x, bv.y, bv.z, bv.w};
#pragma unroll
            for (int r = 0; r < 9; r++) {
                float a = As[kk][ty + r * 16];
#pragma unroll
                for (int c = 0; c < 4; c++) acc[r][c] = fmaf(a, b4[c], acc[r][c]);
            }
        }
        __syncthreads();
    }
#pragma unroll
    for (int r = 0; r < 9; r++) {
        int m = ty + r * 16;
        if (m < SK_M) {
#pragma unroll
            for (int c = 0; c < 4; c++)
                atomicAdd(&C[(long long)m * N + n0 + (tx << 2) + c], acc[r][c]);
        }
    }
}

// h[i] += acc[i] + bias[n]
__global__ void epi_add_kernel(float* __restrict__ h, const float* __restrict__ acc,
                               const float* __restrict__ bias, int N) {
    int i = blockIdx.x * blockDim.x + threadIdx.x;
    if (i >= SK_M * N) return;
    h[i] += acc[i] + bias[i % N];
}

// out[i] = gelu(acc[i] + bias[n])
__global__ void epi_gelu_kernel(float* __restrict__ out, const float* __restrict__ acc,
                                const float* __restrict__ bias, int N) {
    int i = blockIdx.x * blockDim.x + threadIdx.x;
    if (i >= SK_M * N) return;
    float v = acc[i] + bias[i % N];
    out[i] = 0.5f * v * (1.f + erff(v * 0.70710678118654752f));
}

// exact top-20 per row: one wave per row, 8-bit radix select on 32-bit fkey,
// exact lower-index tie-break. Output order arbitrary (consumer is max-reduce).
__launch_bounds__(64)
__global__ void topk_kernel(const float* __restrict__ pd, int* __restrict__ idxo) {
    int row = blockIdx.x;
    int lane = threadIdx.x;
    const float* p = pd + (long long)row * 2048;
    unsigned key[32];
#pragma unroll
    for (int i = 0; i < 8; i++) {
        float4 f = *(const float4*)&p[i * 256 + lane * 4];
        key[i * 4 + 0] = fkey(f.x);
        key[i * 4 + 1] = fkey(f.y);
        key[i * 4 + 2] = fkey(f.z);
        key[i * 4 + 3] = fkey(f.w);
    }
    __shared__ int hist[256];
    __shared__ int ctrl[4];   // [0]=digit, [1]=need, [2]=outcount
    unsigned prefix = 0;
    int need = 20;
    for (int pass = 0; pass < 4; pass++) {
        int shift = 24 - pass * 8;
        for (int t = lane; t < 256; t += 64) hist[t] = 0;
        __syncthreads();
#pragma unroll
        for (int j = 0; j < 32; j++) {
            bool cand = (pass == 0) || ((key[j] >> (shift + 8)) == prefix);
            if (cand) atomicAdd(&hist[(key[j] >> shift) & 255], 1);
        }
        __syncthreads();
        int c0 = hist[4 * lane], c1 = hist[4 * lane + 1];
        int c2 = hist[4 * lane + 2], c3 = hist[4 * lane + 3];
        int lsum = c0 + c1 + c2 + c3;
        int s = lsum;
        for (int off = 1; off < 64; off <<= 1) {
            int t = __shfl_down(s, off);
            if (lane + off < 64) s += t;
        }
        int a3 = s - lsum;       // count of keys in lanes above (higher digits)
        int a2 = a3 + c3;
        int a1 = a2 + c2;
        int a0 = a1 + c1;
        if (a3 < need && a3 + c3 >= need) { ctrl[0] = 4 * lane + 3; ctrl[1] = need - a3; }
        if (a2 < need && a2 + c2 >= need) { ctrl[0] = 4 * lane + 2; ctrl[1] = need - a2; }
        if (a1 < need && a1 + c1 >= need) { ctrl[0] = 4 * lane + 1; ctrl[1] = need - a1; }
        if (a0 < need && a0 + c0 >= need) { ctrl[0] = 4 * lane + 0; ctrl[1] = need - a0; }
        __syncthreads();
        prefix = (prefix << 8) | (unsigned)ctrl[0];
        need = ctrl[1];
        __syncthreads();
    }
    unsigned pivot = prefix;   // full 32-bit key of the 20th element
    if (lane == 0) ctrl[2] = 0;
    __syncthreads();
    int* out = idxo + (long long)row * 20;
#pragma unroll
    for (int j = 0; j < 32; j++) {
        if (key[j] > pivot) {
            int pos = atomicAdd(&ctrl[2], 1);
            out[pos] = (j >> 2) * 256 + lane * 4 + (j & 3);
        }
    }
    __syncthreads();
    int base = ctrl[2];        // = 20 - need
    for (int i = 0; i < 8 && need > 0; i++) {
        int qs[4], nq = 0;
#pragma unroll
        for (int q = 0; q < 4; q++) if (key[i * 4 + q] == pivot) qs[nq++] = q;
        int sc = nq;
        for (int off = 1; off < 64; off <<= 1) {
            int t = __shfl_up(sc, off);
            if (lane >= off) sc += t;
        }
        int excl = sc - nq;
        for (int t2 = 0; t2 < nq; t2++) {
            int pos = excl + t2;
            if (pos < need) out[base + pos] = i * 256 + lane * 4 + qs[t2];
        }
        int chunktotal = __shfl(sc, 63);
        int take = chunktotal < need ? chunktotal : need;
        base += take;
        need -= take;
    }
}

// wcat (2O x C): rows 0..O-1 = w[:, :C]; rows O..2O-1 = w[:, C:] - w[:, :C]; emits f32 + bf16
__global__ void wcat_kernel(const float* __restrict__ w, float* __restrict__ wf,
                            unsigned short* __restrict__ wb, int O, int C) {
    int i = blockIdx.x * blockDim.x + threadIdx.x;
    if (i >= 2 * O * C) return;
    int o2 = i / C, c = i % C;
    float v;
    if (o2 < O) v = w[o2 * 2 * C + c];
    else { int o = o2 - O; v = w[o * 2 * C + C + c] - w[o * 2 * C + c]; }
    wf[i] = v;
    wb[i] = f2bf(v);
}

__global__ void cast_kernel(const float* __restrict__ a, unsigned short* __restrict__ o, int n) {
    int i = blockIdx.x * blockDim.x + threadIdx.x;
    if (i < n) o[i] = f2bf(a[i]);
}

// point-major gather+max
__global__ void gather_max_kernel(const float* __restrict__ Y, const int* __restrict__ idx,
                                  const float* __restrict__ bn,
                                  float* __restrict__ outF, unsigned short* __restrict__ outB,
                                  int O) {
    int i = blockIdx.x * blockDim.x + threadIdx.x;
    if (i >= 2 * 2048 * O) return;
    int o = i % O;
    int t = i / O;
    int n = t & 2047, b = t >> 11;
    const float* Yb = Y + (long long)b * 2048 * (2 * O);
    float center = Yb[(long long)n * (2 * O) + O + o];
    float sc = bn[o], sh = bn[O + o];
    const int* ip = idx + ((long long)b * 2048 + n) * 20;
    float best = -3.0e38f;
#pragma unroll
    for (int k = 0; k < 20; k++) {
        int m = ip[k];
        float y = Yb[(long long)m * (2 * O) + o] + center;
        float v = sc * (y * BN_INVF) + sh;
        v = v > 0.f ? v : 0.2f * v;
        best = fmaxf(best, v);
    }
    long long oo = ((long long)b * 2048 + n) * 512 + o;
    outF[oo] = best;
    outB[oo] = f2bf(best);
}

__global__ void pool_kernel(const float* __restrict__ y5, float* __restrict__ h) {
    int i = blockIdx.x * blockDim.x + threadIdx.x;
    if (i >= 2 * 64 * 1024) return;
    int o = i % 1024;
    int t = i / 1024;
    int p = t & 63, b = t >> 6;
    const float* src = y5 + ((long long)b * 2048 + p * 32) * 1024 + o;
    float mx = src[0];
#pragma unroll
    for (int j = 1; j < 32; j++) mx = fmaxf(mx, src[(long long)j * 1024]);
    h[((long long)b * 65 + 1 + p) * 1024 + o] = mx;
}

__global__ void cls_kernel(const float* __restrict__ cls, float* __restrict__ h) {
    int i = blockIdx.x * blockDim.x + threadIdx.x;
    if (i >= 2 * 1024) return;
    int b = i / 1024, d = i % 1024;
    h[(long long)(b * 65) * 1024 + d] = cls[d];
}

// layernorm per row of 1024; optionally fuse h += pos
__global__ void ln_kernel(float* __restrict__ h, const float* __restrict__ pos,
                          const float* __restrict__ g, const float* __restrict__ bta,
                          float* __restrict__ out, int addpos) {
    __shared__ float sbuf[4];
    int row = blockIdx.x;
    float* x = h + (long long)row * 1024;
    float* o = out + (long long)row * 1024;
    float loc[4];
    float s = 0.f;
#pragma unroll
    for (int i = 0; i < 4; i++) {
        int d = threadIdx.x + i * 256;
        float v = x[d];
        if (addpos) { v += pos[(long long)row * 1024 + d]; x[d] = v; }
        loc[i] = v; s += v;
    }
    float mean = block_sum256(s, sbuf) * (1.f / 1024.f);
    float s2 = 0.f;
#pragma unroll
    for (int i = 0; i < 4; i++) { float d = loc[i] - mean; s2 = fmaf(d, d, s2); }
    float var = block_sum256(s2, sbuf) * (1.f / 1024.f);
    float inv = rsqrtf(var + LN_EPSF);
#pragma unroll
    for (int i = 0; i < 4; i++) {
        int d = threadIdx.x + i * 256;
        o[d] = (loc[i] - mean) * inv * g[d] + bta[d];
    }
}

// one block per (l, head, b)
__global__ void attn_kernel(const float* __restrict__ qkv, float* __restrict__ z) {
    int l = blockIdx.x, hh = blockIdx.y, b = blockIdx.z;
    __shared__ float qs[64];
    __shared__ float sc[65];
    __shared__ float sred[2];
    int tid = threadIdx.x;
    const float* base = qkv + (long long)b * 65 * 1536;
    if (tid < 64) qs[tid] = base[(long long)l * 1536 + hh * 64 + tid];
    __syncthreads();
    if (tid < 65) {
        const float* kp = base + (long long)tid * 1536 + 512 + hh * 64;
        float d = 0.f;
#pragma unroll
        for (int c = 0; c < 64; c++) d = fmaf(qs[c], kp[c], d);
        sc[tid] = d * 0.125f;
    }
    __syncthreads();
    if (tid == 0) { float mx = sc[0]; for (int i = 1; i < 65; i++) mx = fmaxf(mx, sc[i]); sred[0] = mx; }
    __syncthreads();
    if (tid < 65) sc[tid] = expf(sc[tid] - sred[0]);
    __syncthreads();
    if (tid == 0) { float sm = 0.f; for (int i = 0; i < 65; i++) sm += sc[i]; sred[1] = sm; }
    __syncthreads();
    if (tid < 65) sc[tid] = sc[tid] / sred[1];
    __syncthreads();
    if (tid < 64) {
        float a = 0.f;
        const float* vp = base + 1024 + hh * 64 + tid;
        for (int m = 0; m < 65; m++) a = fmaf(sc[m], vp[(long long)m * 1536], a);
        z[((long long)b * 65 + l) * 512 + hh * 64 + tid] = a;
    }
}

__global__ void outcopy_kernel(const float* __restrict__ h, float* __restrict__ out) {
    int i = blockIdx.x * blockDim.x + threadIdx.x;
    if (i >= 2 * 64 * 1024) return;
    int b = i / (64 * 1024), r = i % (64 * 1024);
    out[i] = h[((long long)b * 65 + 1) * 1024 + r];
}

// ---------------- host side ----------------

extern "C" void kernel_launch(void* const* d_in, const int* in_sizes, int n_in,
                              void* d_out, int out_size, void* d_ws, size_t ws_size,
                              hipStream_t stream) {
    const float* x    = (const float*)d_in[0];
    const float* pos  = (const float*)d_in[1];
    const float* cls  = (const float*)d_in[2];
    const float* w1   = (const float*)d_in[3];
    const float* bn1  = (const float*)d_in[4];
    const float* w2   = (const float*)d_in[5];
    const float* bn2  = (const float*)d_in[6];
    const float* w3   = (const float*)d_in[7];
    const float* bn3  = (const float*)d_in[8];
    const float* w4   = (const float*)d_in[9];
    const float* bn4  = (const float*)d_in[10];
    const float* w5   = (const float*)d_in[11];
    const float* bn5  = (const float*)d_in[12];
    const float* ln1  = (const float*)d_in[13];
    const float* wqkv = (const float*)d_in[14];
    const float* wo   = (const float*)d_in[15];
    const float* bo   = (const float*)d_in[16];
    const float* ln2  = (const float*)d_in[17];
    const float* wf1  = (const float*)d_in[18];
    const float* bf1  = (const float*)d_in[19];
    const float* wf2  = (const float*)d_in[20];
    const float* bf2  = (const float*)d_in[21];
    float* outp = (float*)d_out;

    size_t off = 0;
    auto alloc = [&](size_t nbytes) {
        size_t p = off;
        off += (nbytes + 255) & ~(size_t)255;
        return p;
    };
    char* ws = (char*)d_ws;
    float*          xxb    = (float*)(ws + alloc((size_t)2 * 2048 * 4));
    int*            idxb   = (int*)  (ws + alloc((size_t)2 * 2048 * 20 * 4));
    float*          pdb    = (float*)(ws + alloc((size_t)2 * 2048 * 2048 * 4));  // pd -> y5
    float*          wcatF  = (float*)(ws + alloc((size_t)512 * 128 * 4));
    unsigned short* wcatB  = (unsigned short*)(ws + alloc((size_t)512 * 128 * 2));
    float*          Yb     = (float*)(ws + alloc((size_t)2 * 2048 * 512 * 4));
    float*          xcatF  = (float*)(ws + alloc((size_t)2 * 2048 * 512 * 4));
    unsigned short* xcatB  = (unsigned short*)(ws + alloc((size_t)2 * 2048 * 512 * 2));
    unsigned short* w5B    = (unsigned short*)(ws + alloc((size_t)1024 * 512 * 2));
    float*          hbuf   = (float*)(ws + alloc((size_t)2 * 65 * 1024 * 4));
    float*          tbuf   = (float*)(ws + alloc((size_t)2 * 65 * 1024 * 4));
    float*          qkvb   = (float*)(ws + alloc((size_t)2 * 65 * 1536 * 4));
    float*          zbuf   = (float*)(ws + alloc((size_t)2 * 65 * 512 * 4));
    float*          midb   = (float*)(ws + alloc((size_t)2 * 65 * 2048 * 4));
    float*          accb   = (float*)(ws + alloc((size_t)2 * 65 * 2048 * 4));
    (void)ws_size; (void)in_sizes; (void)n_in; (void)out_size;

    // ---- DGCNN patch embed, point-major ----
    struct L { const float* w; const float* bn; int C; int O; int inOff; int outOff; };
    L ls[4] = {
        {w1, bn1, 3,   64,  0,   0},
        {w2, bn2, 64,  64,  0,   64},
        {w3, bn3, 64,  128, 64,  128},
        {w4, bn4, 128, 256, 128, 256},
    };
    for (int l = 0; l < 4; l++) {
        const L& P = ls[l];
        const float* xf;
        int lda; long long bstr;
        if (l == 0) { xf = x; lda = 3; bstr = (long long)2048 * 3; }
        else { xf = xcatF + P.inOff; lda = 512; bstr = (long long)2048 * 512; }

        xx_kernel<<<64, 256, 0, stream>>>(xf, xxb, P.C, lda, bstr);
        {
            dim3 g(2048 / 64, 2048 / 64, 2);
            gemm_nt_kernel<<<g, 256, 0, stream>>>(xf, xf, pdb, xxb,
                                                  2048, 2048, P.C, lda, lda, 2048,
                                                  bstr, bstr, (long long)2048 * 2048, 4);
        }
        topk_kernel<<<2 * 2048, 64, 0, stream>>>(pdb, idxb);
        wcat_kernel<<<(2 * P.O * P.C + 255) / 256, 256, 0, stream>>>(P.w, wcatF, wcatB, P.O, P.C);
        if (l == 0) {
            dim3 g(128 / 64, 2048 / 64, 2);
            gemm_nt_kernel<<<g, 256, 0, stream>>>(xf, wcatF, Yb, nullptr,
                                                  2048, 128, 3, 3, 3, 128,
                                                  bstr, 0, (long long)2048 * 128, 0);
        } else {
            dim3 g((2 * P.O) / 128, 2048 / 128, 2);
            mfma_nt_kernel<<<g, 256, 0, stream>>>(xcatB + P.inOff, wcatB, Yb, nullptr,
                                                  2 * P.O, P.C, 512, P.C, 2 * P.O,
                                                  (long long)2048 * 512, (long long)2048 * 2 * P.O, 0);
        }
        gather_max_kernel<<<(2 * 2048 * P.O + 255) / 256, 256, 0, stream>>>(
            Yb, idxb, P.bn, xcatF + P.outOff, xcatB + P.outOff, P.O);
    }

    // conv5 (bf16 MFMA)
    cast_kernel<<<(1024 * 512 + 255) / 256, 256, 0, stream>>>(w5, w5B, 1024 * 512);
    float* y5 = pdb;
    {
        dim3 g(1024 / 128, 2048 / 128, 2);
        mfma_nt_kernel<<<g, 256, 0, stream>>>(xcatB, w5B, y5, bn5,
                                              1024, 512, 512, 512, 1024,
                                              (long long)2048 * 512, (long long)2048 * 1024, 1);
    }
    pool_kernel<<<(2 * 64 * 1024 + 255) / 256, 256, 0, stream>>>(y5, hbuf);
    cls_kernel<<<(2 * 1024 + 255) / 256, 256, 0, stream>>>(cls, hbuf);

    // ---- transformer (fp32, split-K atomic accumulate) ----
    for (int L = 0; L < 6; L++) {
        const float* ln1g = ln1 + (long long)L * 2048;
        const float* ln2g = ln2 + (long long)L * 2048;
        const float* wqkvL = wqkv + (long long)L * 1024 * 1536;
        const float* woL   = wo   + (long long)L * 512 * 1024;
        const float* boL   = bo   + (long long)L * 1024;
        const float* wf1L  = wf1  + (long long)L * 1024 * 2048;
        const float* bf1L  = bf1  + (long long)L * 2048;
        const float* wf2L  = wf2  + (long long)L * 2048 * 1024;
        const float* bf2L  = bf2  + (long long)L * 1024;

        ln_kernel<<<130, 256, 0, stream>>>(hbuf, pos, ln1g, ln1g + 1024, tbuf, 1);
        hipMemsetAsync(qkvb, 0, (size_t)SK_M * 1536 * 4, stream);
        skinny_atomic_kernel<<<dim3(1536 / 64, 16), 256, 0, stream>>>(tbuf, wqkvL, qkvb, 1536, 1024, 1024, 16);
        attn_kernel<<<dim3(65, 8, 2), 128, 0, stream>>>(qkvb, zbuf);
        hipMemsetAsync(accb, 0, (size_t)SK_M * 1024 * 4, stream);
        skinny_atomic_kernel<<<dim3(1024 / 64, 16), 256, 0, stream>>>(zbuf, woL, accb, 1024, 512, 512, 16);
        epi_add_kernel<<<(SK_M * 1024 + 255) / 256, 256, 0, stream>>>(hbuf, accb, boL, 1024);
        ln_kernel<<<130, 256, 0, stream>>>(hbuf, nullptr, ln2g, ln2g + 1024, tbuf, 0);
        hipMemsetAsync(accb, 0, (size_t)SK_M * 2048 * 4, stream);
        skinny_atomic_kernel<<<dim3(2048 / 64, 8), 256, 0, stream>>>(tbuf, wf1L, accb, 2048, 1024, 1024, 8);
        epi_gelu_kernel<<<(SK_M * 2048 + 255) / 256, 256, 0, stream>>>(midb, accb, bf1L, 2048);
        hipMemsetAsync(accb, 0, (size_t)SK_M * 1024 * 4, stream);
        skinny_atomic_kernel<<<dim3(1024 / 64, 16), 256, 0, stream>>>(midb, wf2L, accb, 1024, 2048, 2048, 16);
        epi_add_kernel<<<(SK_M * 1024 + 255) / 256, 256, 0, stream>>>(hbuf, accb, bf2L, 1024);
    }

    outcopy_kernel<<<(2 * 64 * 1024 + 255) / 256, 256, 0, stream>>>(hbuf, outp);
}

// Round 6
// 971.266 us; speedup vs baseline: 1.8740x; 1.8740x over previous
//
#include <hip/hip_runtime.h>
#include <hip/hip_bf16.h>
#include <math.h>

#define BN_INVF 0.9999950000374998f
#define LN_EPSF 1e-5f

typedef __attribute__((ext_vector_type(8))) short bf16x8;
typedef __attribute__((ext_vector_type(4))) float f32x4;

__device__ inline unsigned short f2bf(float v) {
    __hip_bfloat16 h = __float2bfloat16(v);
    return *(const unsigned short*)&h;
}

// ---------------- small helpers ----------------

__device__ inline float block_sum256(float v, float* sbuf) {
    for (int off = 32; off; off >>= 1) v += __shfl_down(v, off);
    int lane = threadIdx.x & 63, w = threadIdx.x >> 6;
    if (lane == 0) sbuf[w] = v;
    __syncthreads();
    float r;
    if (threadIdx.x == 0) { r = sbuf[0] + sbuf[1] + sbuf[2] + sbuf[3]; sbuf[0] = r; }
    __syncthreads();
    r = sbuf[0];
    __syncthreads();
    return r;
}

__device__ inline unsigned fkey(float v) {
    unsigned u = __float_as_uint(v);
    return (u & 0x80000000u) ? ~u : (u | 0x80000000u);
}

// ---------------- kernels ----------------

// xx[g] = sum_c x[g-row][c]^2, point-major rows; 4 lanes per row
__global__ void xx_kernel(const float* __restrict__ x, float* __restrict__ xx,
                          int C, int lda, long long bstr) {
    int g = blockIdx.x * 64 + (threadIdx.x >> 2);
    int q = threadIdx.x & 3;
    if (g >= 2 * 2048) return;
    int b = g >> 11, n = g & 2047;
    const float* p = x + (long long)b * bstr + (long long)n * lda;
    float s = 0.f;
    for (int c = q; c < C; c += 4) { float v = p[c]; s = fmaf(v, v, s); }
    s += __shfl_down(s, 1);
    s += __shfl_down(s, 2);
    if (q == 0) xx[g] = s;
}

// fp32 NT GEMM: C[m][n] = sum_k A[m][k]*B[n][k].  modes: 0 plain | 4: 2*acc-xx[m]-xx[n]
__launch_bounds__(256)
__global__ void gemm_nt_kernel(const float* __restrict__ A, const float* __restrict__ Bm,
                               float* __restrict__ Cm, const float* __restrict__ vrow,
                               int M, int N, int Kd, int lda, int ldb, int ldc,
                               long long sA, long long sB, long long sC, int mode) {
    int tid = threadIdx.x;
    int tx = tid & 15, ty = tid >> 4;
    int m0 = blockIdx.y * 64, n0 = blockIdx.x * 64;
    A  += (long long)blockIdx.z * sA;
    Bm += (long long)blockIdx.z * sB;
    Cm += (long long)blockIdx.z * sC;

    __shared__ float As[16][68];
    __shared__ float Bs[16][68];
    float acc[4][4] = {};
    const bool vec = ((Kd & 15) == 0);

    for (int k0 = 0; k0 < Kd; k0 += 16) {
        if (vec) {
            int row = tid >> 2, q = tid & 3;
            float4 f = *(const float4*)&A[(long long)(m0 + row) * lda + k0 + q * 4];
            As[q * 4 + 0][row] = f.x; As[q * 4 + 1][row] = f.y;
            As[q * 4 + 2][row] = f.z; As[q * 4 + 3][row] = f.w;
            float4 g = *(const float4*)&Bm[(long long)(n0 + row) * ldb + k0 + q * 4];
            Bs[q * 4 + 0][row] = g.x; Bs[q * 4 + 1][row] = g.y;
            Bs[q * 4 + 2][row] = g.z; Bs[q * 4 + 3][row] = g.w;
        } else {
#pragma unroll
            for (int e = 0; e < 4; e++) {
                int i = tid + e * 256;
                int kk = i & 15, mm = i >> 4;
                int gk = k0 + kk;
                As[kk][mm] = (gk < Kd) ? A[(long long)(m0 + mm) * lda + gk] : 0.f;
            }
#pragma unroll
            for (int e = 0; e < 4; e++) {
                int i = tid + e * 256;
                int kk = i & 15, nn = i >> 4;
                int gk = k0 + kk;
                Bs[kk][nn] = (gk < Kd) ? Bm[(long long)(n0 + nn) * ldb + gk] : 0.f;
            }
        }
        __syncthreads();
#pragma unroll
        for (int kk = 0; kk < 16; kk++) {
            float4 av = *(const float4*)&As[kk][ty * 4];
            float4 bv = *(const float4*)&Bs[kk][tx * 4];
            float a4[4] = {av.x, av.y, av.z, av.w};
            float b4[4] = {bv.x, bv.y, bv.z, bv.w};
#pragma unroll
            for (int i = 0; i < 4; i++)
#pragma unroll
                for (int j = 0; j < 4; j++)
                    acc[i][j] = fmaf(a4[i], b4[j], acc[i][j]);
        }
        __syncthreads();
    }

    const float* xxb = (mode == 4) ? vrow + (long long)blockIdx.z * M : nullptr;
#pragma unroll
    for (int i = 0; i < 4; i++) {
        int m = m0 + ty * 4 + i;
#pragma unroll
        for (int j = 0; j < 4; j++) {
            int n = n0 + tx * 4 + j;
            float v = acc[i][j];
            if (mode == 4) v = 2.f * v - xxb[m] - xxb[n];
            Cm[(long long)m * ldc + n] = v;
        }
    }
}

// bf16 MFMA NT GEMM: 128x128 tile, bk=32. mode 0: plain; 1: lrelu(bn[col]).
__launch_bounds__(256)
__global__ void mfma_nt_kernel(const unsigned short* __restrict__ A,
                               const unsigned short* __restrict__ Bv,
                               float* __restrict__ C, const float* __restrict__ bn,
                               int Nr, int K, int lda, int ldb, int ldc,
                               long long sA, long long sC, int mode) {
    int tid = threadIdx.x;
    int wave = tid >> 6, lane = tid & 63;
    int wm = (wave >> 1) * 64, wn = (wave & 1) * 64;
    int m0 = blockIdx.y * 128, n0 = blockIdx.x * 128;
    A += (long long)blockIdx.z * sA;
    C += (long long)blockIdx.z * sC;

    __shared__ __align__(16) unsigned short As[128 * 40];
    __shared__ __align__(16) unsigned short Bs[128 * 40];
    f32x4 acc[4][4];
#pragma unroll
    for (int i = 0; i < 4; i++)
#pragma unroll
        for (int j = 0; j < 4; j++) acc[i][j] = (f32x4){0.f, 0.f, 0.f, 0.f};

    int lr = lane & 15, lk = (lane >> 4) * 8;

    for (int k0 = 0; k0 < K; k0 += 32) {
#pragma unroll
        for (int e = 0; e < 2; e++) {
            int idx = tid + e * 256;
            int row = idx >> 2, q = idx & 3;
            float4 f = *(const float4*)&A[(long long)(m0 + row) * lda + k0 + q * 8];
            *(float4*)&As[row * 40 + q * 8] = f;
        }
#pragma unroll
        for (int e = 0; e < 2; e++) {
            int idx = tid + e * 256;
            int row = idx >> 2, q = idx & 3;
            float4 f = *(const float4*)&Bv[(long long)(n0 + row) * ldb + k0 + q * 8];
            *(float4*)&Bs[row * 40 + q * 8] = f;
        }
        __syncthreads();
        bf16x8 af[4], bf[4];
#pragma unroll
        for (int t = 0; t < 4; t++) af[t] = *(const bf16x8*)&As[(wm + t * 16 + lr) * 40 + lk];
#pragma unroll
        for (int t = 0; t < 4; t++) bf[t] = *(const bf16x8*)&Bs[(wn + t * 16 + lr) * 40 + lk];
#pragma unroll
        for (int i = 0; i < 4; i++)
#pragma unroll
            for (int j = 0; j < 4; j++)
                acc[i][j] = __builtin_amdgcn_mfma_f32_16x16x32_bf16(af[i], bf[j], acc[i][j], 0, 0, 0);
        __syncthreads();
    }

    int cr = (lane >> 4) << 2;
#pragma unroll
    for (int i = 0; i < 4; i++) {
        int rbase = m0 + wm + i * 16 + cr;
#pragma unroll
        for (int j = 0; j < 4; j++) {
            int col = n0 + wn + j * 16 + (lane & 15);
            float bsc = 0.f, bsh = 0.f;
            if (mode == 1) { bsc = bn[col]; bsh = bn[Nr + col]; }
#pragma unroll
            for (int r = 0; r < 4; r++) {
                float v = acc[i][j][r];
                if (mode == 1) {
                    v = bsc * (v * BN_INVF) + bsh;
                    v = v > 0.f ? v : 0.2f * v;
                }
                C[(long long)(rbase + r) * ldc + col] = v;
            }
        }
    }
}

// transpose+cast weights: wt[n][k] = bf16(w[k][n]); grid (N/32, K/32, layers)
__global__ void wt_kernel(const float* __restrict__ w, unsigned short* __restrict__ wt,
                          int K, int N) {
    __shared__ float t[32][33];
    long long loff = (long long)blockIdx.z * K * N;
    const float* wz = w + loff;
    unsigned short* wtz = wt + loff;
    int n0 = blockIdx.x * 32, k0 = blockIdx.y * 32;
    int tx = threadIdx.x & 31, ty = threadIdx.x >> 5;   // 256 thr: ty 0..7
#pragma unroll
    for (int r = 0; r < 32; r += 8)
        t[ty + r][tx] = wz[(long long)(k0 + ty + r) * N + n0 + tx];
    __syncthreads();
#pragma unroll
    for (int r = 0; r < 32; r += 8)
        wtz[(long long)(n0 + ty + r) * K + k0 + tx] = f2bf(t[tx][ty + r]);
}

// Skinny bf16 MFMA GEMM: A (130 x K bf16) @ Bt (N x K bf16)^T, split-K.
// grid (N/64, S); block = 4 waves; P[(s*144 + m)*N + n] fp32 partials.
__launch_bounds__(256)
__global__ void skinny_mfma_kernel(const unsigned short* __restrict__ A,
                                   const unsigned short* __restrict__ Bt,
                                   float* __restrict__ P, int N, int K, int S) {
    int tid = threadIdx.x;
    int wave = tid >> 6, lane = tid & 63;
    int n0 = blockIdx.x * 64;
    int s = blockIdx.y;
    int kchunk = K / S, k0 = s * kchunk;
    float* Pb = P + (long long)s * 144 * N;

    __shared__ __align__(16) unsigned short As[144 * 40];
    __shared__ __align__(16) unsigned short Bs[64 * 40];
    f32x4 acc[9];
#pragma unroll
    for (int t = 0; t < 9; t++) acc[t] = (f32x4){0.f, 0.f, 0.f, 0.f};

    int lr = lane & 15, lk = (lane >> 4) * 8;
    for (int kc = k0; kc < k0 + kchunk; kc += 32) {
#pragma unroll
        for (int e = 0; e < 3; e++) {
            int idx = tid + e * 256;
            if (idx < 576) {
                int row = idx >> 2, q = idx & 3;
                float4 f = make_float4(0.f, 0.f, 0.f, 0.f);
                if (row < 130) f = *(const float4*)&A[(long long)row * K + kc + q * 8];
                *(float4*)&As[row * 40 + q * 8] = f;
            }
        }
        {
            int row = tid >> 2, q = tid & 3;
            float4 f = *(const float4*)&Bt[(long long)(n0 + row) * K + kc + q * 8];
            *(float4*)&Bs[row * 40 + q * 8] = f;
        }
        __syncthreads();
        bf16x8 bfr = *(const bf16x8*)&Bs[(wave * 16 + lr) * 40 + lk];
#pragma unroll
        for (int t = 0; t < 9; t++) {
            bf16x8 af = *(const bf16x8*)&As[(t * 16 + lr) * 40 + lk];
            acc[t] = __builtin_amdgcn_mfma_f32_16x16x32_bf16(af, bfr, acc[t], 0, 0, 0);
        }
        __syncthreads();
    }
    int cr = (lane >> 4) << 2;
    int col = n0 + wave * 16 + (lane & 15);
#pragma unroll
    for (int t = 0; t < 9; t++) {
        int rbase = t * 16 + cr;
#pragma unroll
        for (int r = 0; r < 4; r++)
            Pb[(long long)(rbase + r) * N + col] = acc[t][r];
    }
}

// reduce partials (stride 144 rows) + epilogue over 130 x N.
// mode 0: C=sum; 1: C += sum+bias[n]; 2: Cb = bf16(gelu(sum+bias[n]))
__global__ void reduce_epi_kernel(const float* __restrict__ P, float* __restrict__ C,
                                  unsigned short* __restrict__ Cb,
                                  const float* __restrict__ bias, int N, int S, int mode) {
    int i = blockIdx.x * blockDim.x + threadIdx.x;
    if (i >= 130 * N) return;
    int n = i % N;
    const float* p = P + i;
    long long stride = (long long)144 * N;
    float s = 0.f;
    for (int ss = 0; ss < S; ss++) s += p[ss * stride];
    if (mode == 0) {
        C[i] = s;
    } else if (mode == 1) {
        C[i] += s + bias[n];
    } else {
        float v = s + bias[n];
        v = 0.5f * v * (1.f + erff(v * 0.70710678118654752f));
        Cb[i] = f2bf(v);
    }
}

// exact top-20 per row: one wave per row, 8-bit radix select on 32-bit fkey,
// exact lower-index tie-break. Output order arbitrary (consumer is max-reduce).
__launch_bounds__(64)
__global__ void topk_kernel(const float* __restrict__ pd, int* __restrict__ idxo) {
    int row = blockIdx.x;
    int lane = threadIdx.x;
    const float* p = pd + (long long)row * 2048;
    unsigned key[32];
#pragma unroll
    for (int i = 0; i < 8; i++) {
        float4 f = *(const float4*)&p[i * 256 + lane * 4];
        key[i * 4 + 0] = fkey(f.x);
        key[i * 4 + 1] = fkey(f.y);
        key[i * 4 + 2] = fkey(f.z);
        key[i * 4 + 3] = fkey(f.w);
    }
    __shared__ int hist[256];
    __shared__ int ctrl[4];
    unsigned prefix = 0;
    int need = 20;
    for (int pass = 0; pass < 4; pass++) {
        int shift = 24 - pass * 8;
        for (int t = lane; t < 256; t += 64) hist[t] = 0;
        __syncthreads();
#pragma unroll
        for (int j = 0; j < 32; j++) {
            bool cand = (pass == 0) || ((key[j] >> (shift + 8)) == prefix);
            if (cand) atomicAdd(&hist[(key[j] >> shift) & 255], 1);
        }
        __syncthreads();
        int c0 = hist[4 * lane], c1 = hist[4 * lane + 1];
        int c2 = hist[4 * lane + 2], c3 = hist[4 * lane + 3];
        int lsum = c0 + c1 + c2 + c3;
        int s = lsum;
        for (int off = 1; off < 64; off <<= 1) {
            int t = __shfl_down(s, off);
            if (lane + off < 64) s += t;
        }
        int a3 = s - lsum;
        int a2 = a3 + c3;
        int a1 = a2 + c2;
        int a0 = a1 + c1;
        if (a3 < need && a3 + c3 >= need) { ctrl[0] = 4 * lane + 3; ctrl[1] = need - a3; }
        if (a2 < need && a2 + c2 >= need) { ctrl[0] = 4 * lane + 2; ctrl[1] = need - a2; }
        if (a1 < need && a1 + c1 >= need) { ctrl[0] = 4 * lane + 1; ctrl[1] = need - a1; }
        if (a0 < need && a0 + c0 >= need) { ctrl[0] = 4 * lane + 0; ctrl[1] = need - a0; }
        __syncthreads();
        prefix = (prefix << 8) | (unsigned)ctrl[0];
        need = ctrl[1];
        __syncthreads();
    }
    unsigned pivot = prefix;
    if (lane == 0) ctrl[2] = 0;
    __syncthreads();
    int* out = idxo + (long long)row * 20;
#pragma unroll
    for (int j = 0; j < 32; j++) {
        if (key[j] > pivot) {
            int pos = atomicAdd(&ctrl[2], 1);
            out[pos] = (j >> 2) * 256 + lane * 4 + (j & 3);
        }
    }
    __syncthreads();
    int base = ctrl[2];
    for (int i = 0; i < 8 && need > 0; i++) {
        int qs[4], nq = 0;
#pragma unroll
        for (int q = 0; q < 4; q++) if (key[i * 4 + q] == pivot) qs[nq++] = q;
        int sc = nq;
        for (int off = 1; off < 64; off <<= 1) {
            int t = __shfl_up(sc, off);
            if (lane >= off) sc += t;
        }
        int excl = sc - nq;
        for (int t2 = 0; t2 < nq; t2++) {
            int pos = excl + t2;
            if (pos < need) out[base + pos] = i * 256 + lane * 4 + qs[t2];
        }
        int chunktotal = __shfl(sc, 63);
        int take = chunktotal < need ? chunktotal : need;
        base += take;
        need -= take;
    }
}

// wcat (2O x C): rows 0..O-1 = w[:, :C]; rows O..2O-1 = w[:, C:] - w[:, :C]; emits f32 + bf16
__global__ void wcat_kernel(const float* __restrict__ w, float* __restrict__ wf,
                            unsigned short* __restrict__ wb, int O, int C) {
    int i = blockIdx.x * blockDim.x + threadIdx.x;
    if (i >= 2 * O * C) return;
    int o2 = i / C, c = i % C;
    float v;
    if (o2 < O) v = w[o2 * 2 * C + c];
    else { int o = o2 - O; v = w[o * 2 * C + C + c] - w[o * 2 * C + c]; }
    wf[i] = v;
    wb[i] = f2bf(v);
}

__global__ void cast_kernel(const float* __restrict__ a, unsigned short* __restrict__ o, int n) {
    int i = blockIdx.x * blockDim.x + threadIdx.x;
    if (i < n) o[i] = f2bf(a[i]);
}

// point-major gather+max
__global__ void gather_max_kernel(const float* __restrict__ Y, const int* __restrict__ idx,
                                  const float* __restrict__ bn,
                                  float* __restrict__ outF, unsigned short* __restrict__ outB,
                                  int O) {
    int i = blockIdx.x * blockDim.x + threadIdx.x;
    if (i >= 2 * 2048 * O) return;
    int o = i % O;
    int t = i / O;
    int n = t & 2047, b = t >> 11;
    const float* Yb = Y + (long long)b * 2048 * (2 * O);
    float center = Yb[(long long)n * (2 * O) + O + o];
    float sc = bn[o], sh = bn[O + o];
    const int* ip = idx + ((long long)b * 2048 + n) * 20;
    float best = -3.0e38f;
#pragma unroll
    for (int k = 0; k < 20; k++) {
        int m = ip[k];
        float y = Yb[(long long)m * (2 * O) + o] + center;
        float v = sc * (y * BN_INVF) + sh;
        v = v > 0.f ? v : 0.2f * v;
        best = fmaxf(best, v);
    }
    long long oo = ((long long)b * 2048 + n) * 512 + o;
    outF[oo] = best;
    outB[oo] = f2bf(best);
}

__global__ void pool_kernel(const float* __restrict__ y5, float* __restrict__ h) {
    int i = blockIdx.x * blockDim.x + threadIdx.x;
    if (i >= 2 * 64 * 1024) return;
    int o = i % 1024;
    int t = i / 1024;
    int p = t & 63, b = t >> 6;
    const float* src = y5 + ((long long)b * 2048 + p * 32) * 1024 + o;
    float mx = src[0];
#pragma unroll
    for (int j = 1; j < 32; j++) mx = fmaxf(mx, src[(long long)j * 1024]);
    h[((long long)b * 65 + 1 + p) * 1024 + o] = mx;
}

__global__ void cls_kernel(const float* __restrict__ cls, float* __restrict__ h) {
    int i = blockIdx.x * blockDim.x + threadIdx.x;
    if (i >= 2 * 1024) return;
    int b = i / 1024, d = i % 1024;
    h[(long long)(b * 65) * 1024 + d] = cls[d];
}

// layernorm per row of 1024 -> bf16 out; optionally fuse h += pos
__global__ void ln_kernel(float* __restrict__ h, const float* __restrict__ pos,
                          const float* __restrict__ g, const float* __restrict__ bta,
                          unsigned short* __restrict__ out, int addpos) {
    __shared__ float sbuf[4];
    int row = blockIdx.x;
    float* x = h + (long long)row * 1024;
    unsigned short* o = out + (long long)row * 1024;
    float loc[4];
    float s = 0.f;
#pragma unroll
    for (int i = 0; i < 4; i++) {
        int d = threadIdx.x + i * 256;
        float v = x[d];
        if (addpos) { v += pos[(long long)row * 1024 + d]; x[d] = v; }
        loc[i] = v; s += v;
    }
    float mean = block_sum256(s, sbuf) * (1.f / 1024.f);
    float s2 = 0.f;
#pragma unroll
    for (int i = 0; i < 4; i++) { float d = loc[i] - mean; s2 = fmaf(d, d, s2); }
    float var = block_sum256(s2, sbuf) * (1.f / 1024.f);
    float inv = rsqrtf(var + LN_EPSF);
#pragma unroll
    for (int i = 0; i < 4; i++) {
        int d = threadIdx.x + i * 256;
        o[d] = f2bf((loc[i] - mean) * inv * g[d] + bta[d]);
    }
}

// one block per (l, head, b); writes bf16 z
__global__ void attn_kernel(const float* __restrict__ qkv, unsigned short* __restrict__ z) {
    int l = blockIdx.x, hh = blockIdx.y, b = blockIdx.z;
    __shared__ float qs[64];
    __shared__ float sc[65];
    __shared__ float sred[2];
    int tid = threadIdx.x;
    const float* base = qkv + (long long)b * 65 * 1536;
    if (tid < 64) qs[tid] = base[(long long)l * 1536 + hh * 64 + tid];
    __syncthreads();
    if (tid < 65) {
        const float* kp = base + (long long)tid * 1536 + 512 + hh * 64;
        float d = 0.f;
#pragma unroll
        for (int c = 0; c < 64; c++) d = fmaf(qs[c], kp[c], d);
        sc[tid] = d * 0.125f;
    }
    __syncthreads();
    if (tid == 0) { float mx = sc[0]; for (int i = 1; i < 65; i++) mx = fmaxf(mx, sc[i]); sred[0] = mx; }
    __syncthreads();
    if (tid < 65) sc[tid] = expf(sc[tid] - sred[0]);
    __syncthreads();
    if (tid == 0) { float sm = 0.f; for (int i = 0; i < 65; i++) sm += sc[i]; sred[1] = sm; }
    __syncthreads();
    if (tid < 65) sc[tid] = sc[tid] / sred[1];
    __syncthreads();
    if (tid < 64) {
        float a = 0.f;
        const float* vp = base + 1024 + hh * 64 + tid;
        for (int m = 0; m < 65; m++) a = fmaf(sc[m], vp[(long long)m * 1536], a);
        z[((long long)b * 65 + l) * 512 + hh * 64 + tid] = f2bf(a);
    }
}

__global__ void outcopy_kernel(const float* __restrict__ h, float* __restrict__ out) {
    int i = blockIdx.x * blockDim.x + threadIdx.x;
    if (i >= 2 * 64 * 1024) return;
    int b = i / (64 * 1024), r = i % (64 * 1024);
    out[i] = h[((long long)b * 65 + 1) * 1024 + r];
}

// ---------------- host side ----------------

extern "C" void kernel_launch(void* const* d_in, const int* in_sizes, int n_in,
                              void* d_out, int out_size, void* d_ws, size_t ws_size,
                              hipStream_t stream) {
    const float* x    = (const float*)d_in[0];
    const float* pos  = (const float*)d_in[1];
    const float* cls  = (const float*)d_in[2];
    const float* w1   = (const float*)d_in[3];
    const float* bn1  = (const float*)d_in[4];
    const float* w2   = (const float*)d_in[5];
    const float* bn2  = (const float*)d_in[6];
    const float* w3   = (const float*)d_in[7];
    const float* bn3  = (const float*)d_in[8];
    const float* w4   = (const float*)d_in[9];
    const float* bn4  = (const float*)d_in[10];
    const float* w5   = (const float*)d_in[11];
    const float* bn5  = (const float*)d_in[12];
    const float* ln1  = (const float*)d_in[13];
    const float* wqkv = (const float*)d_in[14];
    const float* wo   = (const float*)d_in[15];
    const float* bo   = (const float*)d_in[16];
    const float* ln2  = (const float*)d_in[17];
    const float* wf1  = (const float*)d_in[18];
    const float* bf1  = (const float*)d_in[19];
    const float* wf2  = (const float*)d_in[20];
    const float* bf2  = (const float*)d_in[21];
    float* outp = (float*)d_out;

    size_t off = 0;
    auto alloc = [&](size_t nbytes) {
        size_t p = off;
        off += (nbytes + 255) & ~(size_t)255;
        return p;
    };
    char* ws = (char*)d_ws;
    float*          xxb    = (float*)(ws + alloc((size_t)2 * 2048 * 4));
    int*            idxb   = (int*)  (ws + alloc((size_t)2 * 2048 * 20 * 4));
    float*          pdb    = (float*)(ws + alloc((size_t)2 * 2048 * 2048 * 4));  // pd -> y5 -> splitK partials
    float*          wcatF  = (float*)(ws + alloc((size_t)512 * 128 * 4));
    unsigned short* wcatB  = (unsigned short*)(ws + alloc((size_t)512 * 128 * 2));
    float*          Yb     = (float*)(ws + alloc((size_t)2 * 2048 * 512 * 4));
    float*          xcatF  = (float*)(ws + alloc((size_t)2 * 2048 * 512 * 4));
    unsigned short* xcatB  = (unsigned short*)(ws + alloc((size_t)2 * 2048 * 512 * 2));
    unsigned short* w5B    = (unsigned short*)(ws + alloc((size_t)1024 * 512 * 2));
    float*          hbuf   = (float*)(ws + alloc((size_t)2 * 65 * 1024 * 4));
    unsigned short* tbufB  = (unsigned short*)(ws + alloc((size_t)2 * 65 * 1024 * 2));
    float*          qkvb   = (float*)(ws + alloc((size_t)2 * 65 * 1536 * 4));
    unsigned short* zbufB  = (unsigned short*)(ws + alloc((size_t)2 * 65 * 512 * 2));
    unsigned short* midbB  = (unsigned short*)(ws + alloc((size_t)2 * 65 * 2048 * 2));
    unsigned short* wqkvT  = (unsigned short*)(ws + alloc((size_t)6 * 1536 * 1024 * 2));
    unsigned short* woT    = (unsigned short*)(ws + alloc((size_t)6 * 1024 * 512 * 2));
    unsigned short* wf1T   = (unsigned short*)(ws + alloc((size_t)6 * 2048 * 1024 * 2));
    unsigned short* wf2T   = (unsigned short*)(ws + alloc((size_t)6 * 1024 * 2048 * 2));
    (void)ws_size; (void)in_sizes; (void)n_in; (void)out_size;

    // one-time transformer weight transpose+cast (N x K bf16)
    wt_kernel<<<dim3(1536 / 32, 1024 / 32, 6), 256, 0, stream>>>(wqkv, wqkvT, 1024, 1536);
    wt_kernel<<<dim3(1024 / 32, 512 / 32, 6), 256, 0, stream>>>(wo, woT, 512, 1024);
    wt_kernel<<<dim3(2048 / 32, 1024 / 32, 6), 256, 0, stream>>>(wf1, wf1T, 1024, 2048);
    wt_kernel<<<dim3(1024 / 32, 2048 / 32, 6), 256, 0, stream>>>(wf2, wf2T, 2048, 1024);
    cast_kernel<<<(1024 * 512 + 255) / 256, 256, 0, stream>>>(w5, w5B, 1024 * 512);

    // ---- DGCNN patch embed, point-major ----
    struct L { const float* w; const float* bn; int C; int O; int inOff; int outOff; };
    L ls[4] = {
        {w1, bn1, 3,   64,  0,   0},
        {w2, bn2, 64,  64,  0,   64},
        {w3, bn3, 64,  128, 64,  128},
        {w4, bn4, 128, 256, 128, 256},
    };
    for (int l = 0; l < 4; l++) {
        const L& P = ls[l];
        const float* xf;
        int lda; long long bstr;
        if (l == 0) { xf = x; lda = 3; bstr = (long long)2048 * 3; }
        else { xf = xcatF + P.inOff; lda = 512; bstr = (long long)2048 * 512; }

        xx_kernel<<<64, 256, 0, stream>>>(xf, xxb, P.C, lda, bstr);
        {
            dim3 g(2048 / 64, 2048 / 64, 2);
            gemm_nt_kernel<<<g, 256, 0, stream>>>(xf, xf, pdb, xxb,
                                                  2048, 2048, P.C, lda, lda, 2048,
                                                  bstr, bstr, (long long)2048 * 2048, 4);
        }
        topk_kernel<<<2 * 2048, 64, 0, stream>>>(pdb, idxb);
        wcat_kernel<<<(2 * P.O * P.C + 255) / 256, 256, 0, stream>>>(P.w, wcatF, wcatB, P.O, P.C);
        if (l == 0) {
            dim3 g(128 / 64, 2048 / 64, 2);
            gemm_nt_kernel<<<g, 256, 0, stream>>>(xf, wcatF, Yb, nullptr,
                                                  2048, 128, 3, 3, 3, 128,
                                                  bstr, 0, (long long)2048 * 128, 0);
        } else {
            dim3 g((2 * P.O) / 128, 2048 / 128, 2);
            mfma_nt_kernel<<<g, 256, 0, stream>>>(xcatB + P.inOff, wcatB, Yb, nullptr,
                                                  2 * P.O, P.C, 512, P.C, 2 * P.O,
                                                  (long long)2048 * 512, (long long)2048 * 2 * P.O, 0);
        }
        gather_max_kernel<<<(2 * 2048 * P.O + 255) / 256, 256, 0, stream>>>(
            Yb, idxb, P.bn, xcatF + P.outOff, xcatB + P.outOff, P.O);
    }

    // conv5 (bf16 MFMA)
    float* y5 = pdb;
    {
        dim3 g(1024 / 128, 2048 / 128, 2);
        mfma_nt_kernel<<<g, 256, 0, stream>>>(xcatB, w5B, y5, bn5,
                                              1024, 512, 512, 512, 1024,
                                              (long long)2048 * 512, (long long)2048 * 1024, 1);
    }
    pool_kernel<<<(2 * 64 * 1024 + 255) / 256, 256, 0, stream>>>(y5, hbuf);
    cls_kernel<<<(2 * 1024 + 255) / 256, 256, 0, stream>>>(cls, hbuf);

    // ---- transformer (bf16 MFMA skinny, split-K partials) ----
    float* Pbuf = pdb;
    for (int L = 0; L < 6; L++) {
        const float* ln1g = ln1 + (long long)L * 2048;
        const float* ln2g = ln2 + (long long)L * 2048;
        const float* boL  = bo  + (long long)L * 1024;
        const float* bf1L = bf1 + (long long)L * 2048;
        const float* bf2L = bf2 + (long long)L * 1024;
        const unsigned short* wqkvTL = wqkvT + (long long)L * 1536 * 1024;
        const unsigned short* woTL   = woT   + (long long)L * 1024 * 512;
        const unsigned short* wf1TL  = wf1T  + (long long)L * 2048 * 1024;
        const unsigned short* wf2TL  = wf2T  + (long long)L * 1024 * 2048;

        ln_kernel<<<130, 256, 0, stream>>>(hbuf, pos, ln1g, ln1g + 1024, tbufB, 1);
        skinny_mfma_kernel<<<dim3(1536 / 64, 8), 256, 0, stream>>>(tbufB, wqkvTL, Pbuf, 1536, 1024, 8);
        reduce_epi_kernel<<<(130 * 1536 + 255) / 256, 256, 0, stream>>>(Pbuf, qkvb, nullptr, nullptr, 1536, 8, 0);
        attn_kernel<<<dim3(65, 8, 2), 128, 0, stream>>>(qkvb, zbufB);
        skinny_mfma_kernel<<<dim3(1024 / 64, 8), 256, 0, stream>>>(zbufB, woTL, Pbuf, 1024, 512, 8);
        reduce_epi_kernel<<<(130 * 1024 + 255) / 256, 256, 0, stream>>>(Pbuf, hbuf, nullptr, boL, 1024, 8, 1);
        ln_kernel<<<130, 256, 0, stream>>>(hbuf, nullptr, ln2g, ln2g + 1024, tbufB, 0);
        skinny_mfma_kernel<<<dim3(2048 / 64, 8), 256, 0, stream>>>(tbufB, wf1TL, Pbuf, 2048, 1024, 8);
        reduce_epi_kernel<<<(130 * 2048 + 255) / 256, 256, 0, stream>>>(Pbuf, nullptr, midbB, bf1L, 2048, 8, 2);
        skinny_mfma_kernel<<<dim3(1024 / 64, 16), 256, 0, stream>>>(midbB, wf2TL, Pbuf, 1024, 2048, 16);
        reduce_epi_kernel<<<(130 * 1024 + 255) / 256, 256, 0, stream>>>(Pbuf, hbuf, nullptr, bf2L, 1024, 16, 1);
    }

    outcopy_kernel<<<(2 * 64 * 1024 + 255) / 256, 256, 0, stream>>>(hbuf, outp);
}